// Round 1
// baseline (612.333 us; speedup 1.0000x reference)
//
#include <hip/hip_runtime.h>

#define CIN   64
#define COUT  64
#define TT    12
#define FEAT  (CIN * TT)   // 768

__global__ void k_init(float* deg, int* cnt, int n) {
    int i = blockIdx.x * blockDim.x + threadIdx.x;
    if (i < n) { deg[i] = 1.0f; cnt[i] = 0; }
}

__global__ void k_degcnt(const int* __restrict__ src, const int* __restrict__ dst,
                         const float* __restrict__ ea, float* deg, int* cnt, int e_cnt) {
    int e = blockIdx.x * blockDim.x + threadIdx.x;
    if (e < e_cnt) {
        int d = dst[e];
        atomicAdd(&deg[d], ea[e]);
        atomicAdd(&cnt[d], 1);
    }
}

__global__ void k_dis(const float* __restrict__ deg, float* dis, int n) {
    int i = blockIdx.x * blockDim.x + threadIdx.x;
    if (i < n) {
        float d = deg[i];
        dis[i] = (d > 0.0f) ? rsqrtf(d) : 0.0f;
    }
}

// single-block exclusive scan; cnt may alias cursor (read before write, per-element)
__global__ void k_scan(const int* __restrict__ cnt, int* rowptr, int* cursor, int n) {
    __shared__ int part[1024];
    const int T = 1024;
    int t = threadIdx.x;
    int ch = (n + T - 1) / T;
    int begin = t * ch;
    int end = begin + ch; if (end > n) end = n;
    int s = 0;
    for (int i = begin; i < end; ++i) s += cnt[i];
    part[t] = s;
    __syncthreads();
    for (int off = 1; off < T; off <<= 1) {
        int v = (t >= off) ? part[t - off] : 0;
        __syncthreads();
        part[t] += v;
        __syncthreads();
    }
    int run = (t == 0) ? 0 : part[t - 1];
    for (int i = begin; i < end; ++i) {
        int c = cnt[i];                 // read BEFORE aliased write
        rowptr[i] = run; cursor[i] = run;
        run += c;
    }
    if (t == T - 1) rowptr[n] = run;
}

__global__ void k_fill(const int* __restrict__ src, const int* __restrict__ dst,
                       const float* __restrict__ ea, const float* __restrict__ dis,
                       int* cursor, int* csr_src, float* csr_w, int e_cnt) {
    int e = blockIdx.x * blockDim.x + threadIdx.x;
    if (e < e_cnt) {
        int s = src[e], d = dst[e];
        int pos = atomicAdd(&cursor[d], 1);
        csr_src[pos] = s;
        csr_w[pos] = dis[s] * ea[e] * dis[d];
    }
}

__global__ __launch_bounds__(256) void k_conv(
    const float* __restrict__ x, const float* __restrict__ W, const float* __restrict__ b,
    const float* __restrict__ dis, const int* __restrict__ rowptr,
    const int* __restrict__ csr_src, const float* __restrict__ csr_w,
    float* __restrict__ out)
{
    __shared__ float sW[CIN * COUT];
    __shared__ float sAgg[FEAT];
    __shared__ int   sSrc[256];
    __shared__ float sWt[256];
    __shared__ float sB[COUT];

    const int n = blockIdx.x;
    const int t = threadIdx.x;

    for (int i = t; i < CIN * COUT; i += 256) sW[i] = W[i];
    if (t < COUT) sB[t] = b[t];

    const int start = rowptr[n];
    const int end   = rowptr[n + 1];
    const float dn  = dis[n];
    const float selfw = dn * dn;

    const float* xn = x + (size_t)n * FEAT;
    float a0 = xn[t]       * selfw;
    float a1 = xn[t + 256] * selfw;
    float a2 = xn[t + 512] * selfw;

    for (int base = start; base < end; base += 256) {
        int cnt = end - base; if (cnt > 256) cnt = 256;
        __syncthreads();
        if (t < cnt) { sSrc[t] = csr_src[base + t]; sWt[t] = csr_w[base + t]; }
        __syncthreads();
        for (int j = 0; j < cnt; ++j) {
            const float* xs = x + (size_t)sSrc[j] * FEAT;
            float w = sWt[j];
            a0 = fmaf(w, xs[t],       a0);
            a1 = fmaf(w, xs[t + 256], a1);
            a2 = fmaf(w, xs[t + 512], a2);
        }
    }

    sAgg[t] = a0; sAgg[t + 256] = a1; sAgg[t + 512] = a2;
    __syncthreads();

    const int co  = t & 63;
    const int tg  = t >> 6;
    const int tt0 = tg * 3;
    float o0 = sB[co], o1 = o0, o2 = o0;
#pragma unroll
    for (int c = 0; c < CIN; ++c) {
        float wv = sW[c * COUT + co];
        o0 = fmaf(wv, sAgg[c * TT + tt0    ], o0);
        o1 = fmaf(wv, sAgg[c * TT + tt0 + 1], o1);
        o2 = fmaf(wv, sAgg[c * TT + tt0 + 2], o2);
    }
    o0 = fmaxf(o0, 0.0f); o1 = fmaxf(o1, 0.0f); o2 = fmaxf(o2, 0.0f);

    __syncthreads();
    sAgg[co * TT + tt0    ] = o0;
    sAgg[co * TT + tt0 + 1] = o1;
    sAgg[co * TT + tt0 + 2] = o2;
    __syncthreads();
    float* on = out + (size_t)n * FEAT;
    on[t] = sAgg[t]; on[t + 256] = sAgg[t + 256]; on[t + 512] = sAgg[t + 512];
}

extern "C" void kernel_launch(void* const* d_in, const int* in_sizes, int n_in,
                              void* d_out, int out_size, void* d_ws, size_t ws_size,
                              hipStream_t stream) {
    const float* x   = (const float*)d_in[0];
    const int*   ei  = (const int*)d_in[1];
    const float* ea  = (const float*)d_in[2];
    const float* W   = (const float*)d_in[3];
    const float* b   = (const float*)d_in[4];
    float* out = (float*)d_out;

    const int E = in_sizes[2];
    const int N = in_sizes[0] / FEAT;
    const int* src = ei;
    const int* dst = ei + E;

    char* ws = (char*)d_ws;
    float* deg     = (float*)(ws);
    float* dis     = (float*)(ws + (size_t)N * 4);
    int*   rowptr  = (int*)  (ws + (size_t)N * 8);
    int*   cursor  = (int*)  (ws + (size_t)N * 12 + 16);
    int*   csr_src = (int*)  (ws + (size_t)N * 16 + 32);
    float* csr_w   = (float*)(ws + (size_t)N * 16 + 32 + (size_t)E * 4);

    int nb_n = (N + 255) / 256;
    int nb_e = (E + 255) / 256;

    k_init  <<<nb_n, 256, 0, stream>>>(deg, cursor, N);
    k_degcnt<<<nb_e, 256, 0, stream>>>(src, dst, ea, deg, cursor, E);
    k_dis   <<<nb_n, 256, 0, stream>>>(deg, dis, N);
    k_scan  <<<1, 1024, 0, stream>>>(cursor, rowptr, cursor, N);
    k_fill  <<<nb_e, 256, 0, stream>>>(src, dst, ea, dis, cursor, csr_src, csr_w, E);
    k_conv  <<<N, 256, 0, stream>>>(x, W, b, dis, rowptr, csr_src, csr_w, out);
}

// Round 2
// 472.424 us; speedup vs baseline: 1.2961x; 1.2961x over previous
//
#include <hip/hip_runtime.h>

#define CIN   64
#define COUT  64
#define TT    12
#define FEAT  (CIN * TT)   // 768

typedef unsigned int uint32;

// ---------- f32 -> bf16 (RNE) conversion, 4 elems / thread-iter ----------
__global__ __launch_bounds__(256) void k_cvt(const float4* __restrict__ x,
                                             uint2* __restrict__ xh, int nquads) {
    int i = blockIdx.x * blockDim.x + threadIdx.x;
    int stride = gridDim.x * blockDim.x;
    for (; i < nquads; i += stride) {
        float4 v = x[i];
        uint32 u0 = __float_as_uint(v.x), u1 = __float_as_uint(v.y);
        uint32 u2 = __float_as_uint(v.z), u3 = __float_as_uint(v.w);
        u0 = (u0 + 0x7fffu + ((u0 >> 16) & 1)) >> 16;
        u1 = (u1 + 0x7fffu + ((u1 >> 16) & 1)) >> 16;
        u2 = (u2 + 0x7fffu + ((u2 >> 16) & 1)) >> 16;
        u3 = (u3 + 0x7fffu + ((u3 >> 16) & 1)) >> 16;
        uint2 o; o.x = u0 | (u1 << 16); o.y = u2 | (u3 << 16);
        xh[i] = o;
    }
}

// ---------- setup ----------
__global__ void k_init(float* deg, int* cnt, int n) {
    int i = blockIdx.x * blockDim.x + threadIdx.x;
    if (i < n) { deg[i] = 1.0f; cnt[i] = 0; }
}

__global__ void k_degcnt(const int* __restrict__ src, const int* __restrict__ dst,
                         const float* __restrict__ ea, float* deg, int* cnt, int e_cnt) {
    int e = blockIdx.x * blockDim.x + threadIdx.x;
    if (e < e_cnt) {
        int d = dst[e];
        atomicAdd(&deg[d], ea[e]);
        atomicAdd(&cnt[d], 1);
    }
}

__global__ void k_dis(const float* __restrict__ deg, float* dis, int n) {
    int i = blockIdx.x * blockDim.x + threadIdx.x;
    if (i < n) {
        float d = deg[i];
        dis[i] = (d > 0.0f) ? rsqrtf(d) : 0.0f;
    }
}

// single-block exclusive scan; cnt aliases cursor (read before write, per elem)
__global__ void k_scan(const int* __restrict__ cnt, int* rowptr, int* cursor, int n) {
    __shared__ int part[1024];
    const int T = 1024;
    int t = threadIdx.x;
    int ch = (n + T - 1) / T;
    int begin = t * ch;
    int end = begin + ch; if (end > n) end = n;
    int s = 0;
    for (int i = begin; i < end; ++i) s += cnt[i];
    part[t] = s;
    __syncthreads();
    for (int off = 1; off < T; off <<= 1) {
        int v = (t >= off) ? part[t - off] : 0;
        __syncthreads();
        part[t] += v;
        __syncthreads();
    }
    int run = (t == 0) ? 0 : part[t - 1];
    for (int i = begin; i < end; ++i) {
        int c = cnt[i];
        rowptr[i] = run; cursor[i] = run;
        run += c;
    }
    if (t == T - 1) rowptr[n] = run;
}

__global__ void k_fill(const int* __restrict__ src, const int* __restrict__ dst,
                       const float* __restrict__ ea, const float* __restrict__ dis,
                       int* cursor, int2* __restrict__ csr, int e_cnt) {
    int e = blockIdx.x * blockDim.x + threadIdx.x;
    if (e < e_cnt) {
        int s = src[e], d = dst[e];
        int pos = atomicAdd(&cursor[d], 1);
        float w = dis[s] * ea[e] * dis[d];
        int2 p; p.x = s; p.y = __float_as_int(w);
        csr[pos] = p;
    }
}

// ---------- fused aggregate + GEMM + bias + ReLU ----------
// one block per node, 192 threads; thread t owns features [4t, 4t+4)
template <int BF16>
__global__ __launch_bounds__(192) void k_conv(
    const void* __restrict__ xsrc, const float* __restrict__ W,
    const float* __restrict__ b, const float* __restrict__ dis,
    const int* __restrict__ rowptr, const int2* __restrict__ csr,
    float* __restrict__ out)
{
    __shared__ float sAgg[FEAT];   // 3 KB
    __shared__ int2  sE[192];      // 1.5 KB
    __shared__ float sB[COUT];

    const int n = blockIdx.x;
    const int t = threadIdx.x;
    if (t < COUT) sB[t] = b[t];

    const int start = rowptr[n];
    const int end   = rowptr[n + 1];
    const float dn  = dis[n];
    const float selfw = dn * dn;

    float a0, a1, a2, a3;
    if (BF16) {
        const unsigned short* xh = (const unsigned short*)xsrc;
        uint2 v = *((const uint2*)(xh + (size_t)n * FEAT) + t);
        a0 = selfw * __uint_as_float(v.x << 16);
        a1 = selfw * __uint_as_float(v.x & 0xffff0000u);
        a2 = selfw * __uint_as_float(v.y << 16);
        a3 = selfw * __uint_as_float(v.y & 0xffff0000u);
    } else {
        const float* x = (const float*)xsrc;
        float4 v = *((const float4*)(x + (size_t)n * FEAT) + t);
        a0 = selfw * v.x; a1 = selfw * v.y; a2 = selfw * v.z; a3 = selfw * v.w;
    }

    for (int base = start; base < end; base += 192) {
        int cnt = end - base; if (cnt > 192) cnt = 192;
        __syncthreads();
        if (t < cnt) sE[t] = csr[base + t];
        __syncthreads();
        for (int j = 0; j < cnt; ++j) {
            int s    = sE[j].x;
            float w  = __int_as_float(sE[j].y);
            if (BF16) {
                const unsigned short* xh = (const unsigned short*)xsrc;
                uint2 v = *((const uint2*)(xh + (size_t)s * FEAT) + t);
                a0 = fmaf(w, __uint_as_float(v.x << 16),         a0);
                a1 = fmaf(w, __uint_as_float(v.x & 0xffff0000u), a1);
                a2 = fmaf(w, __uint_as_float(v.y << 16),         a2);
                a3 = fmaf(w, __uint_as_float(v.y & 0xffff0000u), a3);
            } else {
                const float* x = (const float*)xsrc;
                float4 v = *((const float4*)(x + (size_t)s * FEAT) + t);
                a0 = fmaf(w, v.x, a0); a1 = fmaf(w, v.y, a1);
                a2 = fmaf(w, v.z, a2); a3 = fmaf(w, v.w, a3);
            }
        }
    }

    float4 av; av.x = a0; av.y = a1; av.z = a2; av.w = a3;
    *((float4*)&sAgg[4 * t]) = av;       // feature f = c*12 + tt layout
    __syncthreads();

    // per-node GEMM from LDS agg; W stays in L1 (hot 16 KB, shared by all blocks)
    const int co  = t & 63;
    const int tg  = t >> 6;              // 0..2 (wave-uniform)
    const int tt0 = tg * 4;
    float o0 = sB[co], o1 = o0, o2 = o0, o3 = o0;
#pragma unroll
    for (int c = 0; c < CIN; ++c) {
        float wv = W[c * COUT + co];
        o0 = fmaf(wv, sAgg[c * TT + tt0    ], o0);
        o1 = fmaf(wv, sAgg[c * TT + tt0 + 1], o1);
        o2 = fmaf(wv, sAgg[c * TT + tt0 + 2], o2);
        o3 = fmaf(wv, sAgg[c * TT + tt0 + 3], o3);
    }
    o0 = fmaxf(o0, 0.0f); o1 = fmaxf(o1, 0.0f);
    o2 = fmaxf(o2, 0.0f); o3 = fmaxf(o3, 0.0f);

    __syncthreads();
    float4 ov; ov.x = o0; ov.y = o1; ov.z = o2; ov.w = o3;
    *((float4*)&sAgg[co * TT + tt0]) = ov;   // co*12+tt0 ≡ 0 (mod 4) -> aligned
    __syncthreads();
    *((float4*)(out + (size_t)n * FEAT + 4 * t)) = *((const float4*)&sAgg[4 * t]);
}

// ---------- launch ----------
extern "C" void kernel_launch(void* const* d_in, const int* in_sizes, int n_in,
                              void* d_out, int out_size, void* d_ws, size_t ws_size,
                              hipStream_t stream) {
    const float* x   = (const float*)d_in[0];
    const int*   ei  = (const int*)d_in[1];
    const float* ea  = (const float*)d_in[2];
    const float* W   = (const float*)d_in[3];
    const float* b   = (const float*)d_in[4];
    float* out = (float*)d_out;

    const int E = in_sizes[2];
    const int N = in_sizes[0] / FEAT;
    const int* src = ei;
    const int* dst = ei + E;

    // workspace carve-up, 16B-aligned chunks
    size_t off = 0;
    char* ws = (char*)d_ws;
    auto alloc = [&](size_t bytes) -> char* {
        char* p = ws + off;
        off = (off + bytes + 15) & ~(size_t)15;
        return p;
    };
    float* deg     = (float*)alloc((size_t)N * 4);
    float* dis     = (float*)alloc((size_t)N * 4);
    int*   rowptr  = (int*)  alloc((size_t)(N + 1) * 4);
    int*   cursor  = (int*)  alloc((size_t)N * 4);          // doubles as cnt
    int2*  csr     = (int2*) alloc((size_t)E * 8);
    size_t xh_off  = off;
    unsigned short* xh = (unsigned short*)alloc((size_t)N * FEAT * 2);
    const bool use_bf16 = (off <= ws_size);
    (void)xh_off;

    int nb_n = (N + 255) / 256;
    int nb_e = (E + 255) / 256;

    if (use_bf16) {
        int nquads = (N * FEAT) / 4;
        k_cvt<<<2048, 256, 0, stream>>>((const float4*)x, (uint2*)xh, nquads);
    }
    k_init  <<<nb_n, 256, 0, stream>>>(deg, cursor, N);
    k_degcnt<<<nb_e, 256, 0, stream>>>(src, dst, ea, deg, cursor, E);
    k_dis   <<<nb_n, 256, 0, stream>>>(deg, dis, N);
    k_scan  <<<1, 1024, 0, stream>>>(cursor, rowptr, cursor, N);
    k_fill  <<<nb_e, 256, 0, stream>>>(src, dst, ea, dis, cursor, csr, E);
    if (use_bf16)
        k_conv<1><<<N, 192, 0, stream>>>(xh, W, b, dis, rowptr, csr, out);
    else
        k_conv<0><<<N, 192, 0, stream>>>(x,  W, b, dis, rowptr, csr, out);
}

// Round 3
// 355.106 us; speedup vs baseline: 1.7244x; 1.3304x over previous
//
#include <hip/hip_runtime.h>

#define CIN   64
#define COUT  64
#define TT    12
#define FEAT  (CIN * TT)   // 768
#define QROW  (FEAT / 4)   // 192 uint2 (4 bf16) per row

typedef unsigned int uint32;
typedef unsigned long long u64;

#define DEG_SCALE 1048576.0f   // 2^20 fixed point for edge-weight sums

// ---------- f32 -> bf16 (RNE), 4 elems / iter ----------
__global__ __launch_bounds__(256) void k_cvt(const float4* __restrict__ x,
                                             uint2* __restrict__ xh, int nquads) {
    int i = blockIdx.x * blockDim.x + threadIdx.x;
    int stride = gridDim.x * blockDim.x;
    for (; i < nquads; i += stride) {
        float4 v = x[i];
        uint32 u0 = __float_as_uint(v.x), u1 = __float_as_uint(v.y);
        uint32 u2 = __float_as_uint(v.z), u3 = __float_as_uint(v.w);
        u0 = (u0 + 0x7fffu + ((u0 >> 16) & 1)) >> 16;
        u1 = (u1 + 0x7fffu + ((u1 >> 16) & 1)) >> 16;
        u2 = (u2 + 0x7fffu + ((u2 >> 16) & 1)) >> 16;
        u3 = (u3 + 0x7fffu + ((u3 >> 16) & 1)) >> 16;
        uint2 o; o.x = u0 | (u1 << 16); o.y = u2 | (u3 << 16);
        xh[i] = o;
    }
}

// ---------- degree: one u64 atomic (cnt in hi32, fixed-point ea-sum in lo32) ----------
__global__ void k_deg(const int* __restrict__ dst, const float* __restrict__ ea,
                      u64* __restrict__ deg64, int e_cnt) {
    int e = blockIdx.x * blockDim.x + threadIdx.x;
    if (e < e_cnt) {
        u64 v = ((u64)1 << 32) | (u64)(uint32)(ea[e] * DEG_SCALE + 0.5f);
        atomicAdd(&deg64[dst[e]], v);
    }
}

// ---------- dis = rsqrt(1 + sum_ea); block-reduce cnt into partial[] ----------
__global__ __launch_bounds__(256) void k_disred(const u64* __restrict__ deg64,
                                                float* __restrict__ dis,
                                                int* __restrict__ partial, int n) {
    __shared__ int red[256];
    int t = threadIdx.x;
    int i = blockIdx.x * 256 + t;
    int cnt = 0;
    if (i < n) {
        u64 v = deg64[i];
        cnt = (int)(v >> 32);
        float deg = 1.0f + (float)(uint32)v * (1.0f / DEG_SCALE);
        dis[i] = rsqrtf(deg);
    }
    red[t] = cnt;
    __syncthreads();
    for (int off = 128; off > 0; off >>= 1) {
        if (t < off) red[t] += red[t + off];
        __syncthreads();
    }
    if (t == 0) partial[blockIdx.x] = red[0];
}

// ---------- scan the per-block partials (nb <= 1024); write total to rowptr[N] ----------
__global__ __launch_bounds__(1024) void k_scanpart(int* __restrict__ partial, int nb,
                                                   int* __restrict__ rowptrN) {
    __shared__ int tmp[1024];
    int t = threadIdx.x;
    int v = (t < nb) ? partial[t] : 0;
    tmp[t] = v;
    __syncthreads();
    for (int off = 1; off < 1024; off <<= 1) {
        int u = (t >= off) ? tmp[t - off] : 0;
        __syncthreads();
        tmp[t] += u;
        __syncthreads();
    }
    if (t < nb) partial[t] = tmp[t] - v;   // exclusive block offset
    if (t == 1023) *rowptrN = tmp[1023];   // grand total
}

// ---------- per-element exclusive scan + block offset -> rowptr, cursor ----------
__global__ __launch_bounds__(256) void k_scanwrite(const u64* __restrict__ deg64,
                                                   const int* __restrict__ partial,
                                                   int* __restrict__ rowptr,
                                                   int* __restrict__ cursor, int n) {
    __shared__ int tmp[256];
    int t = threadIdx.x;
    int i = blockIdx.x * 256 + t;
    int v = (i < n) ? (int)(deg64[i] >> 32) : 0;
    tmp[t] = v;
    __syncthreads();
    for (int off = 1; off < 256; off <<= 1) {
        int u = (t >= off) ? tmp[t - off] : 0;
        __syncthreads();
        tmp[t] += u;
        __syncthreads();
    }
    int excl = tmp[t] - v + partial[blockIdx.x];
    if (i < n) { rowptr[i] = excl; cursor[i] = excl; }
}

// ---------- scatter edges into CSR slots ----------
__global__ void k_fill(const int* __restrict__ src, const int* __restrict__ dst,
                       const float* __restrict__ ea, const float* __restrict__ dis,
                       int* __restrict__ cursor, int2* __restrict__ csr, int e_cnt) {
    int e = blockIdx.x * blockDim.x + threadIdx.x;
    if (e < e_cnt) {
        int s = src[e], d = dst[e];
        int pos = atomicAdd(&cursor[d], 1);
        float w = dis[s] * ea[e] * dis[d];
        int2 p; p.x = s; p.y = __float_as_int(w);
        csr[pos] = p;
    }
}

// ---------- fused aggregate + GEMM + bias + ReLU ----------
// one block per node, 192 threads; thread t owns features [4t, 4t+4)
// no LDS edge staging: csr index is wave-uniform -> broadcast/scalar load
template <int BF16>
__global__ __launch_bounds__(192) void k_conv(
    const void* __restrict__ xsrc, const float* __restrict__ W,
    const float* __restrict__ b, const float* __restrict__ dis,
    const int* __restrict__ rowptr, const int2* __restrict__ csr,
    float* __restrict__ out)
{
    __shared__ float sAgg[FEAT];   // 3 KB
    __shared__ float sB[COUT];

    const int n = blockIdx.x;
    const int t = threadIdx.x;
    if (t < COUT) sB[t] = b[t];

    const int start = rowptr[n];
    const int end   = rowptr[n + 1];
    const float dn  = dis[n];
    const float selfw = dn * dn;

    float a0, a1, a2, a3;
    if (BF16) {
        const uint2* xb = (const uint2*)xsrc;
        uint2 v = xb[(size_t)n * QROW + t];
        a0 = selfw * __uint_as_float(v.x << 16);
        a1 = selfw * __uint_as_float(v.x & 0xffff0000u);
        a2 = selfw * __uint_as_float(v.y << 16);
        a3 = selfw * __uint_as_float(v.y & 0xffff0000u);
    } else {
        const float4* xb = (const float4*)xsrc;
        float4 v = xb[(size_t)n * QROW + t];
        a0 = selfw * v.x; a1 = selfw * v.y; a2 = selfw * v.z; a3 = selfw * v.w;
    }

    for (int e = start; e < end; ++e) {
        int2 p = csr[e];                     // wave-uniform -> broadcast
        int s   = p.x;
        float w = __int_as_float(p.y);
        if (BF16) {
            const uint2* xb = (const uint2*)xsrc;
            uint2 v = xb[(size_t)s * QROW + t];
            a0 = fmaf(w, __uint_as_float(v.x << 16),         a0);
            a1 = fmaf(w, __uint_as_float(v.x & 0xffff0000u), a1);
            a2 = fmaf(w, __uint_as_float(v.y << 16),         a2);
            a3 = fmaf(w, __uint_as_float(v.y & 0xffff0000u), a3);
        } else {
            const float4* xb = (const float4*)xsrc;
            float4 v = xb[(size_t)s * QROW + t];
            a0 = fmaf(w, v.x, a0); a1 = fmaf(w, v.y, a1);
            a2 = fmaf(w, v.z, a2); a3 = fmaf(w, v.w, a3);
        }
    }

    float4 av; av.x = a0; av.y = a1; av.z = a2; av.w = a3;
    *((float4*)&sAgg[4 * t]) = av;
    __syncthreads();

    const int co  = t & 63;
    const int tg  = t >> 6;              // wave-uniform
    const int tt0 = tg * 4;
    float o0 = sB[co], o1 = o0, o2 = o0, o3 = o0;
#pragma unroll
    for (int c = 0; c < CIN; ++c) {
        float wv = W[c * COUT + co];     // hot 16 KB in L1
        o0 = fmaf(wv, sAgg[c * TT + tt0    ], o0);
        o1 = fmaf(wv, sAgg[c * TT + tt0 + 1], o1);
        o2 = fmaf(wv, sAgg[c * TT + tt0 + 2], o2);
        o3 = fmaf(wv, sAgg[c * TT + tt0 + 3], o3);
    }
    o0 = fmaxf(o0, 0.0f); o1 = fmaxf(o1, 0.0f);
    o2 = fmaxf(o2, 0.0f); o3 = fmaxf(o3, 0.0f);

    __syncthreads();
    float4 ov; ov.x = o0; ov.y = o1; ov.z = o2; ov.w = o3;
    *((float4*)&sAgg[co * TT + tt0]) = ov;
    __syncthreads();
    *((float4*)(out + (size_t)n * FEAT + 4 * t)) = *((const float4*)&sAgg[4 * t]);
}

// ---------- launch ----------
extern "C" void kernel_launch(void* const* d_in, const int* in_sizes, int n_in,
                              void* d_out, int out_size, void* d_ws, size_t ws_size,
                              hipStream_t stream) {
    const float* x   = (const float*)d_in[0];
    const int*   ei  = (const int*)d_in[1];
    const float* ea  = (const float*)d_in[2];
    const float* W   = (const float*)d_in[3];
    const float* b   = (const float*)d_in[4];
    float* out = (float*)d_out;

    const int E = in_sizes[2];
    const int N = in_sizes[0] / FEAT;
    const int* src = ei;
    const int* dst = ei + E;

    size_t off = 0;
    char* ws = (char*)d_ws;
    auto alloc = [&](size_t bytes) -> char* {
        char* p = ws + off;
        off = (off + bytes + 15) & ~(size_t)15;
        return p;
    };
    u64*   deg64   = (u64*)  alloc((size_t)N * 8);
    float* dis     = (float*)alloc((size_t)N * 4);
    int*   rowptr  = (int*)  alloc((size_t)(N + 1) * 4);
    int*   cursor  = (int*)  alloc((size_t)N * 4);
    int*   partial = (int*)  alloc(4096);
    int2*  csr     = (int2*) alloc((size_t)E * 8);
    unsigned short* xh = (unsigned short*)alloc((size_t)N * FEAT * 2);
    const bool use_bf16 = (off <= ws_size);

    int nb_e = (E + 255) / 256;
    int nb_n = (N + 255) / 256;    // 196 for N=50000; must be <= 1024

    hipMemsetAsync(deg64, 0, (size_t)N * 8, stream);
    if (use_bf16) {
        int nquads = (N * FEAT) / 4;
        k_cvt<<<2048, 256, 0, stream>>>((const float4*)x, (uint2*)xh, nquads);
    }
    k_deg      <<<nb_e, 256, 0, stream>>>(dst, ea, deg64, E);
    k_disred   <<<nb_n, 256, 0, stream>>>(deg64, dis, partial, N);
    k_scanpart <<<1, 1024, 0, stream>>>(partial, nb_n, rowptr + N);
    k_scanwrite<<<nb_n, 256, 0, stream>>>(deg64, partial, rowptr, cursor, N);
    k_fill     <<<nb_e, 256, 0, stream>>>(src, dst, ea, dis, cursor, csr, E);
    if (use_bf16)
        k_conv<1><<<N, 192, 0, stream>>>(xh, W, b, dis, rowptr, csr, out);
    else
        k_conv<0><<<N, 192, 0, stream>>>(x,  W, b, dis, rowptr, csr, out);
}

// Round 5
// 326.701 us; speedup vs baseline: 1.8743x; 1.0869x over previous
//
#include <hip/hip_runtime.h>

#define CIN   64
#define COUT  64
#define TT    12
#define FEAT  (CIN * TT)   // 768
#define QROW  (FEAT / 4)   // 192 uint2 (4 bf16) per row

typedef unsigned int uint32;
typedef unsigned long long u64;
typedef float  __attribute__((ext_vector_type(4))) f32x4;   // native vec for nontemporal builtins

#define DEG_SCALE 1048576.0f   // 2^20 fixed point for edge-weight sums

// ---------- fused: f32->bf16 convert (blocks [0,nbCvt)) + degree atomics ----------
__global__ __launch_bounds__(256) void k_cvt_deg(
    const f32x4* __restrict__ x, uint2* __restrict__ xh, int nquads, int nbCvt,
    const int* __restrict__ dst, const float* __restrict__ ea,
    u64* __restrict__ deg64, int e_cnt)
{
    int bid = blockIdx.x;
    if (bid < nbCvt) {
        int i = bid * 256 + threadIdx.x;
        int stride = nbCvt * 256;
        for (; i < nquads; i += stride) {
            f32x4 v = __builtin_nontemporal_load(&x[i]);   // read-once stream
            uint32 u0 = __float_as_uint(v.x), u1 = __float_as_uint(v.y);
            uint32 u2 = __float_as_uint(v.z), u3 = __float_as_uint(v.w);
            u0 = (u0 + 0x7fffu + ((u0 >> 16) & 1)) >> 16;
            u1 = (u1 + 0x7fffu + ((u1 >> 16) & 1)) >> 16;
            u2 = (u2 + 0x7fffu + ((u2 >> 16) & 1)) >> 16;
            u3 = (u3 + 0x7fffu + ((u3 >> 16) & 1)) >> 16;
            uint2 o; o.x = u0 | (u1 << 16); o.y = u2 | (u3 << 16);
            xh[i] = o;                                       // keep in cache (re-read)
        }
    } else {
        int e = (bid - nbCvt) * 256 + threadIdx.x;
        if (e < e_cnt) {
            u64 v = ((u64)1 << 32) | (u64)(uint32)(ea[e] * DEG_SCALE + 0.5f);
            atomicAdd(&deg64[dst[e]], v);
        }
    }
}

// ---------- dis = rsqrt(1 + sum_ea); block-reduce cnt into partial[] ----------
__global__ __launch_bounds__(256) void k_disred(const u64* __restrict__ deg64,
                                                float* __restrict__ dis,
                                                int* __restrict__ partial, int n) {
    __shared__ int red[256];
    int t = threadIdx.x;
    int i = blockIdx.x * 256 + t;
    int cnt = 0;
    if (i < n) {
        u64 v = deg64[i];
        cnt = (int)(v >> 32);
        float deg = 1.0f + (float)(uint32)v * (1.0f / DEG_SCALE);
        dis[i] = rsqrtf(deg);
    }
    red[t] = cnt;
    __syncthreads();
    for (int off = 128; off > 0; off >>= 1) {
        if (t < off) red[t] += red[t + off];
        __syncthreads();
    }
    if (t == 0) partial[blockIdx.x] = red[0];
}

// ---------- per-element scan; each block redundantly reduces partial[] ----------
// nb (number of partials) must be <= 256
__global__ __launch_bounds__(256) void k_scanwrite(const u64* __restrict__ deg64,
                                                   const int* __restrict__ partial,
                                                   int nb,
                                                   int* __restrict__ rowptr,
                                                   int* __restrict__ cursor, int n) {
    __shared__ int tmp[256];
    __shared__ int pred[256];
    int t = threadIdx.x;
    int bid = blockIdx.x;
    int i = bid * 256 + t;

    int pv = (t < nb) ? partial[t] : 0;
    pred[t] = (t < bid) ? pv : 0;          // sum of partials before this block
    int v = (i < n) ? (int)(deg64[i] >> 32) : 0;
    tmp[t] = v;
    __syncthreads();
    for (int off = 128; off > 0; off >>= 1) {
        if (t < off) pred[t] += pred[t + off];
        __syncthreads();
    }
    for (int off = 1; off < 256; off <<= 1) {
        int u = (t >= off) ? tmp[t - off] : 0;
        __syncthreads();
        tmp[t] += u;
        __syncthreads();
    }
    int blockOff = pred[0];
    int excl = tmp[t] - v + blockOff;
    if (i < n) { rowptr[i] = excl; cursor[i] = excl; }
    if (bid == nb - 1 && t == 255) rowptr[n] = blockOff + tmp[255];
}

// ---------- scatter edges into CSR slots ----------
__global__ void k_fill(const int* __restrict__ src, const int* __restrict__ dst,
                       const float* __restrict__ ea, const float* __restrict__ dis,
                       int* __restrict__ cursor, int2* __restrict__ csr, int e_cnt) {
    int e = blockIdx.x * blockDim.x + threadIdx.x;
    if (e < e_cnt) {
        int s = src[e], d = dst[e];
        int pos = atomicAdd(&cursor[d], 1);
        float w = dis[s] * ea[e] * dis[d];
        int2 p; p.x = s; p.y = __float_as_int(w);
        csr[pos] = p;
    }
}

// ---------- fused aggregate + GEMM + bias + ReLU ----------
// one block per node, 192 threads; thread t owns features [4t, 4t+4)
// LDS-staged edge descriptors (R1 structure: proven fastest)
template <int BF16>
__global__ __launch_bounds__(192) void k_conv(
    const void* __restrict__ xsrc, const float* __restrict__ W,
    const float* __restrict__ b, const float* __restrict__ dis,
    const int* __restrict__ rowptr, const int2* __restrict__ csr,
    float* __restrict__ out)
{
    __shared__ float sAgg[FEAT];   // 3 KB
    __shared__ int2  sE[192];      // 1.5 KB
    __shared__ float sB[COUT];

    const int n = blockIdx.x;
    const int t = threadIdx.x;
    if (t < COUT) sB[t] = b[t];

    const int start = rowptr[n];
    const int end   = rowptr[n + 1];
    const float dn  = dis[n];
    const float selfw = dn * dn;

    float a0, a1, a2, a3;
    if (BF16) {
        const uint2* xb = (const uint2*)xsrc;
        uint2 v = xb[(size_t)n * QROW + t];
        a0 = selfw * __uint_as_float(v.x << 16);
        a1 = selfw * __uint_as_float(v.x & 0xffff0000u);
        a2 = selfw * __uint_as_float(v.y << 16);
        a3 = selfw * __uint_as_float(v.y & 0xffff0000u);
    } else {
        const f32x4* xb = (const f32x4*)xsrc;
        f32x4 v = xb[(size_t)n * QROW + t];
        a0 = selfw * v.x; a1 = selfw * v.y; a2 = selfw * v.z; a3 = selfw * v.w;
    }

    for (int base = start; base < end; base += 192) {
        int cnt = end - base; if (cnt > 192) cnt = 192;
        __syncthreads();
        if (t < cnt) sE[t] = csr[base + t];
        __syncthreads();
        for (int j = 0; j < cnt; ++j) {
            int s    = sE[j].x;
            float w  = __int_as_float(sE[j].y);
            if (BF16) {
                const uint2* xb = (const uint2*)xsrc;
                uint2 v = xb[(size_t)s * QROW + t];
                a0 = fmaf(w, __uint_as_float(v.x << 16),         a0);
                a1 = fmaf(w, __uint_as_float(v.x & 0xffff0000u), a1);
                a2 = fmaf(w, __uint_as_float(v.y << 16),         a2);
                a3 = fmaf(w, __uint_as_float(v.y & 0xffff0000u), a3);
            } else {
                const f32x4* xb = (const f32x4*)xsrc;
                f32x4 v = xb[(size_t)s * QROW + t];
                a0 = fmaf(w, v.x, a0); a1 = fmaf(w, v.y, a1);
                a2 = fmaf(w, v.z, a2); a3 = fmaf(w, v.w, a3);
            }
        }
    }

    float4 av; av.x = a0; av.y = a1; av.z = a2; av.w = a3;
    *((float4*)&sAgg[4 * t]) = av;
    __syncthreads();

    const int co  = t & 63;
    const int tg  = t >> 6;              // wave-uniform
    const int tt0 = tg * 4;
    float o0 = sB[co], o1 = o0, o2 = o0, o3 = o0;
#pragma unroll
    for (int c = 0; c < CIN; ++c) {
        float wv = W[c * COUT + co];     // hot 16 KB in L1/L2
        o0 = fmaf(wv, sAgg[c * TT + tt0    ], o0);
        o1 = fmaf(wv, sAgg[c * TT + tt0 + 1], o1);
        o2 = fmaf(wv, sAgg[c * TT + tt0 + 2], o2);
        o3 = fmaf(wv, sAgg[c * TT + tt0 + 3], o3);
    }
    o0 = fmaxf(o0, 0.0f); o1 = fmaxf(o1, 0.0f);
    o2 = fmaxf(o2, 0.0f); o3 = fmaxf(o3, 0.0f);

    __syncthreads();
    float4 ov; ov.x = o0; ov.y = o1; ov.z = o2; ov.w = o3;
    *((float4*)&sAgg[co * TT + tt0]) = ov;
    __syncthreads();
    // nontemporal: don't let the 150 MB output stream evict x_bf16 from L2/L3
    f32x4 r = *((const f32x4*)&sAgg[4 * t]);
    __builtin_nontemporal_store(r, (f32x4*)(out + (size_t)n * FEAT + 4 * t));
}

// ---------- launch ----------
extern "C" void kernel_launch(void* const* d_in, const int* in_sizes, int n_in,
                              void* d_out, int out_size, void* d_ws, size_t ws_size,
                              hipStream_t stream) {
    const float* x   = (const float*)d_in[0];
    const int*   ei  = (const int*)d_in[1];
    const float* ea  = (const float*)d_in[2];
    const float* W   = (const float*)d_in[3];
    const float* b   = (const float*)d_in[4];
    float* out = (float*)d_out;

    const int E = in_sizes[2];
    const int N = in_sizes[0] / FEAT;
    const int* src = ei;
    const int* dst = ei + E;

    size_t off = 0;
    char* ws = (char*)d_ws;
    auto alloc = [&](size_t bytes) -> char* {
        char* p = ws + off;
        off = (off + bytes + 15) & ~(size_t)15;
        return p;
    };
    u64*   deg64   = (u64*)  alloc((size_t)N * 8);
    float* dis     = (float*)alloc((size_t)N * 4);
    int*   rowptr  = (int*)  alloc((size_t)(N + 1) * 4);
    int*   cursor  = (int*)  alloc((size_t)N * 4);
    int*   partial = (int*)  alloc(4096);
    int2*  csr     = (int2*) alloc((size_t)E * 8);
    unsigned short* xh = (unsigned short*)alloc((size_t)N * FEAT * 2);
    const bool use_bf16 = (off <= ws_size);

    int nb_e = (E + 255) / 256;
    int nb_n = (N + 255) / 256;    // 196 for N=50000; must be <= 256 for k_scanwrite

    (void)hipMemsetAsync(deg64, 0, (size_t)N * 8, stream);
    if (use_bf16) {
        int nquads = (N * FEAT) / 4;
        int nbCvt = 1024;
        k_cvt_deg<<<nbCvt + nb_e, 256, 0, stream>>>((const f32x4*)x, (uint2*)xh,
                                                    nquads, nbCvt, dst, ea, deg64, E);
    } else {
        k_cvt_deg<<<nb_e, 256, 0, stream>>>(nullptr, nullptr, 0, 0, dst, ea, deg64, E);
    }
    k_disred   <<<nb_n, 256, 0, stream>>>(deg64, dis, partial, N);
    k_scanwrite<<<nb_n, 256, 0, stream>>>(deg64, partial, nb_n, rowptr, cursor, N);
    k_fill     <<<nb_e, 256, 0, stream>>>(src, dst, ea, dis, cursor, csr, E);
    if (use_bf16)
        k_conv<1><<<N, 192, 0, stream>>>(xh, W, b, dis, rowptr, csr, out);
    else
        k_conv<0><<<N, 192, 0, stream>>>(x,  W, b, dis, rowptr, csr, out);
}